// Round 2
// baseline (120.413 us; speedup 1.0000x reference)
//
#include <hip/hip_runtime.h>

// B=64, C=1024, H=W=32 -> HW=1024. x is fp32 [B,C,H,W] = 256 MiB.
// Strategy: read x ONCE. Block = (batch b, hw-tile of 16). Each of 256
// threads holds x[b, c0..c0+3, hw0..hw0+15] (64 floats) in registers.
//  - scores for the 16 hw (sum over C via shfl+LDS reduce); bias dropped
//    (softmax is shift-invariant).
//  - local softmax: m_t, Z_t, unnormalized e[k] = exp(s_k - m_t)
//  - unnormalized pooled partial: acc[c] = sum_k x[c,k] * e[k]   (registers)
// Combine kernel rescales partials by exp(m_t - m_g)/Z_g and sums over tiles.
#define NB 64
#define NC 1024
#define NHW 1024
#define THW 16              // hw elements per tile
#define NT (NHW / THW)      // 64 tiles per batch
#define CPT 4               // channels per thread (NC / 256)

__global__ __launch_bounds__(256) void fused_partial_kernel(
        const float* __restrict__ x, const float* __restrict__ w,
        float* __restrict__ partial, float* __restrict__ mz) {
    __shared__ float red[4][THW];
    __shared__ float pbuf[THW];

    const int tid  = threadIdx.x;
    const int wave = tid >> 6, lane = tid & 63;
    const int bid  = blockIdx.x;        // = b*NT + t
    const int b    = bid >> 6;
    const int hw0  = (bid & 63) * THW;
    const int c0   = tid * CPT;

    // Load tile into registers: 4 channels x 16 hw = 16 float4.
    // Per-lane stride is 4 KB but each lane consumes a full 64B line
    // over its 4 consecutive float4s -> full line utilization.
    float4 xv[CPT][THW / 4];
    #pragma unroll
    for (int j = 0; j < CPT; ++j) {
        const float* row = x + ((size_t)(b * NC + c0 + j) * NHW + hw0);
        #pragma unroll
        for (int k = 0; k < THW / 4; ++k)
            xv[j][k] = reinterpret_cast<const float4*>(row)[k];
    }
    float wj[CPT];
    #pragma unroll
    for (int j = 0; j < CPT; ++j) wj[j] = w[c0 + j];

    // Partial scores over this thread's 4 channels, for all 16 hw.
    float sp[THW];
    #pragma unroll
    for (int k = 0; k < THW; ++k) sp[k] = 0.0f;
    #pragma unroll
    for (int j = 0; j < CPT; ++j) {
        #pragma unroll
        for (int k = 0; k < THW / 4; ++k) {
            sp[4 * k + 0] += xv[j][k].x * wj[j];
            sp[4 * k + 1] += xv[j][k].y * wj[j];
            sp[4 * k + 2] += xv[j][k].z * wj[j];
            sp[4 * k + 3] += xv[j][k].w * wj[j];
        }
    }
    // Reduce over the 64 lanes of each wave (sums 256 channels/wave).
    #pragma unroll
    for (int k = 0; k < THW; ++k) {
        #pragma unroll
        for (int off = 32; off; off >>= 1)
            sp[k] += __shfl_xor(sp[k], off);
    }
    if (lane == 0) {
        #pragma unroll
        for (int k = 0; k < THW; ++k) red[wave][k] = sp[k];
    }
    __syncthreads();

    // First 16 threads: finish reduce, local softmax (unnormalized).
    if (tid < THW) {
        float s = red[0][tid] + red[1][tid] + red[2][tid] + red[3][tid];
        float m = s;
        #pragma unroll
        for (int off = 8; off; off >>= 1) m = fmaxf(m, __shfl_xor(m, off, 16));
        float e = __expf(s - m);
        float z = e;
        #pragma unroll
        for (int off = 8; off; off >>= 1) z += __shfl_xor(z, off, 16);
        pbuf[tid] = e;
        if (tid == 0) {
            mz[2 * bid]     = m;
            mz[2 * bid + 1] = z;
        }
    }
    __syncthreads();

    // Unnormalized pooled partial from registers.
    float pb[THW];
    #pragma unroll
    for (int k = 0; k < THW; ++k) pb[k] = pbuf[k];   // LDS broadcast reads

    float4 o;
    float a[CPT];
    #pragma unroll
    for (int j = 0; j < CPT; ++j) {
        a[j] = 0.0f;
        #pragma unroll
        for (int k = 0; k < THW / 4; ++k) {
            a[j] += xv[j][k].x * pb[4 * k + 0];
            a[j] += xv[j][k].y * pb[4 * k + 1];
            a[j] += xv[j][k].z * pb[4 * k + 2];
            a[j] += xv[j][k].w * pb[4 * k + 3];
        }
    }
    o.x = a[0]; o.y = a[1]; o.z = a[2]; o.w = a[3];
    reinterpret_cast<float4*>(partial + (size_t)bid * NC + c0)[0] = o;
}

// Combine: out[b,c] = sum_t partial[b,t,c] * exp(m_t - m_g) / Z_g
// grid = NB * (NC/256) = 256 blocks, 256 threads (thread = one c).
__global__ __launch_bounds__(256) void combine_kernel(
        const float* __restrict__ partial, const float* __restrict__ mz,
        float* __restrict__ out) {
    __shared__ float scale[NT];
    const int tid = threadIdx.x;
    const int b   = blockIdx.x >> 2;
    const int c   = ((blockIdx.x & 3) << 8) + tid;

    if (tid < NT) {   // NT == 64 == one full wave
        const float m_t = mz[2 * (b * NT + tid)];
        const float Z_t = mz[2 * (b * NT + tid) + 1];
        float m = m_t;
        #pragma unroll
        for (int off = 32; off; off >>= 1) m = fmaxf(m, __shfl_xor(m, off));
        const float ew = __expf(m_t - m);
        float z = Z_t * ew;
        #pragma unroll
        for (int off = 32; off; off >>= 1) z += __shfl_xor(z, off);
        scale[tid] = ew / z;
    }
    __syncthreads();

    float acc = 0.0f;
    const float* p = partial + (size_t)b * NT * NC + c;
    #pragma unroll 8
    for (int t = 0; t < NT; ++t)
        acc += p[(size_t)t * NC] * scale[t];
    out[b * NC + c] = acc;
}

extern "C" void kernel_launch(void* const* d_in, const int* in_sizes, int n_in,
                              void* d_out, int out_size, void* d_ws, size_t ws_size,
                              hipStream_t stream) {
    const float* x = (const float*)d_in[0];
    const float* w = (const float*)d_in[1];
    // d_in[2] (bias) is mathematically irrelevant: softmax(s + b) == softmax(s).
    float* out     = (float*)d_out;
    float* partial = (float*)d_ws;                         // 64*64*1024 f32 = 16 MiB
    float* mz      = partial + (size_t)NB * NT * NC;       // 8192 f32

    fused_partial_kernel<<<NB * NT, 256, 0, stream>>>(x, w, partial, mz);
    combine_kernel<<<NB * (NC / 256), 256, 0, stream>>>(partial, mz, out);
}

// Round 3
// 98.864 us; speedup vs baseline: 1.2180x; 1.2180x over previous
//
#include <hip/hip_runtime.h>

// B=64, C=1024, H=W=32 -> HW=1024. x fp32 [B,C,H,W] = 256 MiB. Read x ONCE.
// Block = (b, hw-tile of 16), 256 threads, grid 4096.
// COALESCED register tile: instruction i loads channels 64*i + (tid>>2);
// lane&3 selects the 16B chunk of the 64B row x[b,c,hw0:hw0+16] -> every
// wave load = 16 fully-consumed cache lines (fixes R2's 16KB lane stride,
// which touched 64 lines at 16B each and was L1-transaction-bound).
//  Phase A (scores): partial over thread's channels, shfl_xor {4,8,16,32}
//    sums over lane>>2 (channel groups), LDS for cross-wave; local softmax.
//  Phase B (pool): dot(xv, e) per channel, shfl_xor {1,2} sums the 4
//    hw-chunks; distributed coalesced store of unnormalized partials.
// Combine kernel rescales by exp(m_t - m_g)/Z_g and sums tiles.
#define NB 64
#define NC 1024
#define NHW 1024
#define THW 16
#define NT (NHW / THW)   // 64 tiles per batch

__global__ __launch_bounds__(256) void fused_partial_kernel(
        const float* __restrict__ x, const float* __restrict__ w,
        float* __restrict__ partial, float* __restrict__ mz) {
    __shared__ float red[4][THW];
    __shared__ float pbuf[THW];

    const int tid  = threadIdx.x;
    const int wave = tid >> 6, lane = tid & 63;
    const int bid  = blockIdx.x;        // = b*NT + t
    const int b    = bid >> 6;
    const int hw0  = (bid & 63) * THW;
    const int cg   = tid >> 2;          // channel sub-index 0..63
    const int m    = lane & 3;          // 16B chunk within the 64B row

    // xv[i] = x[b, 64*i + cg, hw0 + 4*m .. +3]
    const float* base = x + ((size_t)(b * NC + cg)) * NHW + hw0 + m * 4;
    float4 xv[16];
    float  wj[16];
    #pragma unroll
    for (int i = 0; i < 16; ++i) {
        xv[i] = *reinterpret_cast<const float4*>(base + (size_t)i * 64 * NHW);
        wj[i] = w[cg + (i << 6)];
    }

    // ---- Phase A: scores for the 16 hw of this tile ----
    float sp[4] = {0.f, 0.f, 0.f, 0.f};
    #pragma unroll
    for (int i = 0; i < 16; ++i) {
        sp[0] += xv[i].x * wj[i];
        sp[1] += xv[i].y * wj[i];
        sp[2] += xv[i].z * wj[i];
        sp[3] += xv[i].w * wj[i];
    }
    #pragma unroll
    for (int k = 0; k < 4; ++k) {       // sum over lane>>2 (16 channel groups)
        #pragma unroll
        for (int off = 4; off < 64; off <<= 1)
            sp[k] += __shfl_xor(sp[k], off);
    }
    if (lane < 4) {                     // lane == m holds hw chunk m
        #pragma unroll
        for (int k = 0; k < 4; ++k) red[wave][lane * 4 + k] = sp[k];
    }
    __syncthreads();

    // local softmax over the 16 tile scores (bias dropped: shift-invariant)
    if (tid < THW) {
        float s = red[0][tid] + red[1][tid] + red[2][tid] + red[3][tid];
        float mx = s;
        #pragma unroll
        for (int off = 8; off; off >>= 1) mx = fmaxf(mx, __shfl_xor(mx, off, 16));
        float e = __expf(s - mx);
        float z = e;
        #pragma unroll
        for (int off = 8; off; off >>= 1) z += __shfl_xor(z, off, 16);
        pbuf[tid] = e;
        if (tid == 0) {
            mz[2 * bid]     = mx;
            mz[2 * bid + 1] = z;
        }
    }
    __syncthreads();

    // ---- Phase B: unnormalized pooled partials ----
    const float4 ev = *reinterpret_cast<const float4*>(&pbuf[m * 4]);
    #pragma unroll
    for (int i = 0; i < 16; ++i) {
        float t = xv[i].x * ev.x + xv[i].y * ev.y + xv[i].z * ev.z + xv[i].w * ev.w;
        t += __shfl_xor(t, 1);          // sum the 4 hw-chunks (lane&3)
        t += __shfl_xor(t, 2);
        if ((i & 3) == m)               // one writer per channel, distributed
            partial[(size_t)bid * NC + (i << 6) + cg] = t;
    }
}

// out[b,c] = sum_t partial[b,t,c] * exp(m_t - m_g) / Z_g
// grid = NB * (NC/256) = 256 blocks, 256 threads (thread = one c).
__global__ __launch_bounds__(256) void combine_kernel(
        const float* __restrict__ partial, const float* __restrict__ mz,
        float* __restrict__ out) {
    __shared__ float scale[NT];
    const int tid = threadIdx.x;
    const int b   = blockIdx.x >> 2;
    const int c   = ((blockIdx.x & 3) << 8) + tid;

    if (tid < NT) {                     // NT == 64 == one full wave
        const float m_t = mz[2 * (b * NT + tid)];
        const float Z_t = mz[2 * (b * NT + tid) + 1];
        float mg = m_t;
        #pragma unroll
        for (int off = 32; off; off >>= 1) mg = fmaxf(mg, __shfl_xor(mg, off));
        const float ew = __expf(m_t - mg);
        float z = Z_t * ew;
        #pragma unroll
        for (int off = 32; off; off >>= 1) z += __shfl_xor(z, off);
        scale[tid] = ew / z;
    }
    __syncthreads();

    float acc = 0.0f;
    const float* p = partial + (size_t)b * NT * NC + c;
    #pragma unroll 8
    for (int t = 0; t < NT; ++t)
        acc += p[(size_t)t * NC] * scale[t];
    out[b * NC + c] = acc;
}

extern "C" void kernel_launch(void* const* d_in, const int* in_sizes, int n_in,
                              void* d_out, int out_size, void* d_ws, size_t ws_size,
                              hipStream_t stream) {
    const float* x = (const float*)d_in[0];
    const float* w = (const float*)d_in[1];
    // d_in[2] (bias) is irrelevant under softmax (shift-invariance).
    float* out     = (float*)d_out;
    float* partial = (float*)d_ws;                    // 64*64*1024 f32 = 16 MiB
    float* mz      = partial + (size_t)NB * NT * NC;  // 8192 f32

    fused_partial_kernel<<<NB * NT, 256, 0, stream>>>(x, w, partial, mz);
    combine_kernel<<<NB * (NC / 256), 256, 0, stream>>>(partial, mz, out);
}

// Round 4
// 85.135 us; speedup vs baseline: 1.4144x; 1.1613x over previous
//
#include <hip/hip_runtime.h>

// B=64, C=1024, H=W=32 -> HW=1024. x fp32 [B,C,H,W] = 256 MiB (= L3 size).
// Two-pass, roofline ~520 MiB traffic; lever = Infinity-Cache reuse on pass 2.
//  K1: (b, c-chunk of 64) blocks, grid 1024 (4 blocks/CU), each streams a
//      CONTIGUOUS 256 KB slab; partial scores per chunk -> partials[b][16][HW].
//  K2: per-batch merge of 16 partials + softmax -> attn[b][HW].
//  K3: pool, wave-per-channel (contiguous 4 KB rows), block order REVERSED
//      so it reads the most-recently-cached lines first (L3 LRU exploit).
#define NB 64
#define NC 1024
#define NHW 1024
#define NCHUNK 16              // c-chunks per batch
#define CCH 64                 // channels per chunk

__device__ inline float wave_reduce_max(float v) {
    #pragma unroll
    for (int off = 32; off; off >>= 1) v = fmaxf(v, __shfl_xor(v, off));
    return v;
}
__device__ inline float wave_reduce_sum(float v) {
    #pragma unroll
    for (int off = 32; off; off >>= 1) v += __shfl_xor(v, off);
    return v;
}

// K1: partials[b*16+chunk][hw] = sum_{c in chunk} x[b,c,hw] * w[c]
// grid = NB*NCHUNK = 1024 blocks, 256 threads; thread owns hw = 4t..4t+3.
__global__ __launch_bounds__(256) void scores_partial_kernel(
        const float* __restrict__ x, const float* __restrict__ w,
        float* __restrict__ partials) {
    const int tid   = threadIdx.x;
    const int b     = blockIdx.x >> 4;
    const int chunk = blockIdx.x & 15;
    const int c0    = chunk * CCH;
    const float* xb = x + ((size_t)(b * NC + c0)) * NHW + tid * 4;

    float4 ps = {0.f, 0.f, 0.f, 0.f};
    #pragma unroll 8
    for (int k = 0; k < CCH; ++k) {
        const float4 v = *reinterpret_cast<const float4*>(xb + (size_t)k * NHW);
        const float wk = w[c0 + k];            // wave-uniform -> scalar load
        ps.x += v.x * wk; ps.y += v.y * wk;
        ps.z += v.z * wk; ps.w += v.w * wk;
    }
    reinterpret_cast<float4*>(partials + (size_t)blockIdx.x * NHW)[tid] = ps;
}

// K2: merge 16 partials per batch, softmax over NHW -> attn.
// grid = NB, 256 threads; thread owns hw = 4t..4t+3. Bias dropped
// (softmax shift-invariance).
__global__ __launch_bounds__(256) void softmax_kernel(
        const float* __restrict__ partials, float* __restrict__ attn) {
    __shared__ float redm[4];
    __shared__ float reds[4];
    const int tid  = threadIdx.x;
    const int wave = tid >> 6, lane = tid & 63;
    const int b    = blockIdx.x;

    float4 s = {0.f, 0.f, 0.f, 0.f};
    #pragma unroll
    for (int i = 0; i < NCHUNK; ++i) {
        const float4 p = reinterpret_cast<const float4*>(
            partials + (size_t)(b * NCHUNK + i) * NHW)[tid];
        s.x += p.x; s.y += p.y; s.z += p.z; s.w += p.w;
    }

    float m = fmaxf(fmaxf(s.x, s.y), fmaxf(s.z, s.w));
    m = wave_reduce_max(m);
    if (lane == 0) redm[wave] = m;
    __syncthreads();
    m = fmaxf(fmaxf(redm[0], redm[1]), fmaxf(redm[2], redm[3]));

    float4 e;
    e.x = __expf(s.x - m); e.y = __expf(s.y - m);
    e.z = __expf(s.z - m); e.w = __expf(s.w - m);
    float z = e.x + e.y + e.z + e.w;
    z = wave_reduce_sum(z);
    if (lane == 0) reds[wave] = z;
    __syncthreads();
    const float inv = 1.0f / (reds[0] + reds[1] + reds[2] + reds[3]);

    e.x *= inv; e.y *= inv; e.z *= inv; e.w *= inv;
    reinterpret_cast<float4*>(attn + (size_t)b * NHW)[tid] = e;
}

// K3: out[b,c] = sum_hw x[b,c,hw] * attn[b,hw]; wave-per-channel.
// Block order REVERSED (L3 recency). grid = NB*NC/4 = 16384, 256 threads.
__global__ __launch_bounds__(256) void pool_kernel(
        const float* __restrict__ x, const float* __restrict__ attn,
        float* __restrict__ out) {
    const int rbid = (NB * NC / 4 - 1) - blockIdx.x;   // reversed dispatch
    const int wave = threadIdx.x >> 6;
    const int lane = threadIdx.x & 63;
    const int out_idx = (rbid << 2) + wave;            // = b*NC + c
    const int b = out_idx >> 10;                       // NC = 1024
    const float4* xr = reinterpret_cast<const float4*>(x + (size_t)out_idx * NHW);
    const float4* ar = reinterpret_cast<const float4*>(attn + (size_t)b * NHW);

    float acc = 0.0f;
    #pragma unroll
    for (int i = 0; i < 4; ++i) {                      // 4 * 64 lanes * 4 floats
        const float4 xv = xr[(i << 6) + lane];
        const float4 av = ar[(i << 6) + lane];
        acc += xv.x * av.x + xv.y * av.y + xv.z * av.z + xv.w * av.w;
    }
    acc = wave_reduce_sum(acc);
    if (lane == 0) out[out_idx] = acc;
}

extern "C" void kernel_launch(void* const* d_in, const int* in_sizes, int n_in,
                              void* d_out, int out_size, void* d_ws, size_t ws_size,
                              hipStream_t stream) {
    const float* x = (const float*)d_in[0];
    const float* w = (const float*)d_in[1];
    // d_in[2] (bias) irrelevant under softmax (shift-invariance).
    float* out      = (float*)d_out;
    float* partials = (float*)d_ws;                          // 4 MiB
    float* attn     = partials + (size_t)NB * NCHUNK * NHW;  // 256 KiB

    scores_partial_kernel<<<NB * NCHUNK, 256, 0, stream>>>(x, w, partials);
    softmax_kernel<<<NB, 256, 0, stream>>>(partials, attn);
    pool_kernel<<<(NB * NC) / 4, 256, 0, stream>>>(x, attn, out);
}